// Round 15
// baseline (176.573 us; speedup 1.0000x reference)
//
#include <hip/hip_runtime.h>
#include <hip/hip_bf16.h>
#include <math.h>

#define HW2D 25600      // 160*160
#define NB 8
#define NC 256
#define CR 64
#define H_ 160
#define W_ 160

typedef short bf16x8 __attribute__((ext_vector_type(8)));
typedef float f32x4 __attribute__((ext_vector_type(4)));

__device__ __forceinline__ short f2bf(float f) {
    __hip_bfloat16 h = __float2bfloat16(f);   // v_cvt_pk_bf16_f32 pairs
    return *reinterpret_cast<short*>(&h);
}
__device__ __forceinline__ float bf2f(unsigned short b) {
    union { unsigned u; float f; } v; v.u = ((unsigned)b) << 16;
    return v.f;
}

// ---- pack reduce_w into MFMA A-fragment order: aPack[(s*4+m)*64+lane][8] ----
__global__ __launch_bounds__(256) void k_pack(const float* __restrict__ rw,
                                              short* __restrict__ aPack) {
    int t = blockIdx.x * 256 + threadIdx.x;   // 0..2047
    if (t >= 2048) return;
    int s = t >> 8, m = (t >> 6) & 3, lane = t & 63;
    int row = m * 16 + (lane & 15);           // output o within [0,64)
    int k0 = s * 32 + (lane >> 4) * 8;        // channel c
    short* dst = aPack + ((size_t)((s * 4 + m) * 64 + lane)) * 8;
#pragma unroll
    for (int j = 0; j < 8; ++j)
        dst[j] = f2bf(rw[row * NC + k0 + j]);
}

// ---- y1[b,px,o] (NHWC bf16) = sum_c W[o,c]*x[b,c,px] via MFMA --------------
// ONE WAVE PER BLOCK (64 threads, 64 px), grid 3200: no barriers, no
// cross-wave LDS; finer granularity (12.5 blocks/CU). dwordx4 x-loads with
// B-column remap px = pxb + 4c + n. Emits per-block GN partials
// part[blk*128 + {0..63 sum, 64..127 sumsq}] from the SAME bf16-rounded values.
__global__ __launch_bounds__(64) void k_rmfma(const float* __restrict__ x,
                                              const short* __restrict__ aPack,
                                              unsigned short* __restrict__ y1,
                                              float* __restrict__ part) {
    int lane = threadIdx.x;                        // 0..63
    int blk = blockIdx.x;                          // 0..3199
    int b = blk / 400;
    int pxb = (blk - b * 400) * 64;                // 64 px per block/wave
    int l15 = lane & 15, kg = lane >> 4;
    int laneoff = kg * 8 * HW2D + 4 * l15;         // per-lane 32-bit offset
    const float* xw = x + (size_t)b * NC * HW2D + pxb;   // SGPR base
    f32x4 acc[4][4];
    f32x4 zz = {0.f, 0.f, 0.f, 0.f};
#pragma unroll
    for (int m = 0; m < 4; ++m)
#pragma unroll
        for (int n = 0; n < 4; ++n) acc[m][n] = zz;
    const bf16x8* ap = (const bf16x8*)aPack + lane;
#pragma unroll
    for (int s = 0; s < 8; ++s) {
        bf16x8 a0 = ap[(s * 4 + 0) * 64];
        bf16x8 a1 = ap[(s * 4 + 1) * 64];
        bf16x8 a2 = ap[(s * 4 + 2) * 64];
        bf16x8 a3 = ap[(s * 4 + 3) * 64];
        const float* xs = xw + s * 32 * HW2D + laneoff;
        bf16x8 b0, b1, b2, b3;
#pragma unroll
        for (int j = 0; j < 8; ++j) {
            float4 v = *(const float4*)(xs + (size_t)j * HW2D);
            b0[j] = f2bf(v.x);                 // px = pxb + 4*l15 + 0
            b1[j] = f2bf(v.y);                 // px = pxb + 4*l15 + 1
            b2[j] = f2bf(v.z);                 // px = pxb + 4*l15 + 2
            b3[j] = f2bf(v.w);                 // px = pxb + 4*l15 + 3
        }
        acc[0][0] = __builtin_amdgcn_mfma_f32_16x16x32_bf16(a0, b0, acc[0][0], 0, 0, 0);
        acc[0][1] = __builtin_amdgcn_mfma_f32_16x16x32_bf16(a0, b1, acc[0][1], 0, 0, 0);
        acc[0][2] = __builtin_amdgcn_mfma_f32_16x16x32_bf16(a0, b2, acc[0][2], 0, 0, 0);
        acc[0][3] = __builtin_amdgcn_mfma_f32_16x16x32_bf16(a0, b3, acc[0][3], 0, 0, 0);
        acc[1][0] = __builtin_amdgcn_mfma_f32_16x16x32_bf16(a1, b0, acc[1][0], 0, 0, 0);
        acc[1][1] = __builtin_amdgcn_mfma_f32_16x16x32_bf16(a1, b1, acc[1][1], 0, 0, 0);
        acc[1][2] = __builtin_amdgcn_mfma_f32_16x16x32_bf16(a1, b2, acc[1][2], 0, 0, 0);
        acc[1][3] = __builtin_amdgcn_mfma_f32_16x16x32_bf16(a1, b3, acc[1][3], 0, 0, 0);
        acc[2][0] = __builtin_amdgcn_mfma_f32_16x16x32_bf16(a2, b0, acc[2][0], 0, 0, 0);
        acc[2][1] = __builtin_amdgcn_mfma_f32_16x16x32_bf16(a2, b1, acc[2][1], 0, 0, 0);
        acc[2][2] = __builtin_amdgcn_mfma_f32_16x16x32_bf16(a2, b2, acc[2][2], 0, 0, 0);
        acc[2][3] = __builtin_amdgcn_mfma_f32_16x16x32_bf16(a2, b3, acc[2][3], 0, 0, 0);
        acc[3][0] = __builtin_amdgcn_mfma_f32_16x16x32_bf16(a3, b0, acc[3][0], 0, 0, 0);
        acc[3][1] = __builtin_amdgcn_mfma_f32_16x16x32_bf16(a3, b1, acc[3][1], 0, 0, 0);
        acc[3][2] = __builtin_amdgcn_mfma_f32_16x16x32_bf16(a3, b2, acc[3][2], 0, 0, 0);
        acc[3][3] = __builtin_amdgcn_mfma_f32_16x16x32_bf16(a3, b3, acc[3][3], 0, 0, 0);
    }
    // --- transpose 64px x 64ch to NHWC via wave-private LDS (pad 66) ---------
    // In-order DS ops within the single wave: no barrier needed (same
    // mechanism the 4-wave version relied on between write and readback).
    __shared__ unsigned short trw[64 * 66];        // 8448 B
#pragma unroll
    for (int m = 0; m < 4; ++m)
#pragma unroll
        for (int n = 0; n < 4; ++n)
#pragma unroll
            for (int i = 0; i < 4; i += 2) {
                unsigned short r0 = (unsigned short)f2bf(acc[m][n][i]);
                unsigned short r1 = (unsigned short)f2bf(acc[m][n][i + 1]);
                unsigned v = (unsigned)r0 | ((unsigned)r1 << 16);
                int o = m * 16 + kg * 4 + i;              // even
                *(unsigned*)&trw[(4 * l15 + n) * 66 + o] = v;
            }
    // readback px-slot-major + coalesced NHWC stores + stats accumulation
    float cs[8], cq[8];
#pragma unroll
    for (int k = 0; k < 8; ++k) { cs[k] = 0.f; cq[k] = 0.f; }
    unsigned short* yg = y1 + ((size_t)b * HW2D + pxb) * 64;
    const int e = lane & 7, a = lane >> 3;
#pragma unroll
    for (int j = 0; j < 8; ++j) {
        int p = j * 8 + a;                                // px slot 0..63
        int dbase = p * 66 + e * 8;                       // even ushort idx
        unsigned q0 = *(const unsigned*)&trw[dbase];
        unsigned q1 = *(const unsigned*)&trw[dbase + 2];
        unsigned q2 = *(const unsigned*)&trw[dbase + 4];
        unsigned q3 = *(const unsigned*)&trw[dbase + 6];
        uint4 vv; vv.x = q0; vv.y = q1; vv.z = q2; vv.w = q3;
        *(uint4*)(yg + (size_t)p * 64 + e * 8) = vv;
        float f0 = bf2f((unsigned short)(q0 & 0xffff)), f1 = bf2f((unsigned short)(q0 >> 16));
        float f2 = bf2f((unsigned short)(q1 & 0xffff)), f3 = bf2f((unsigned short)(q1 >> 16));
        float f4 = bf2f((unsigned short)(q2 & 0xffff)), f5 = bf2f((unsigned short)(q2 >> 16));
        float f6 = bf2f((unsigned short)(q3 & 0xffff)), f7 = bf2f((unsigned short)(q3 >> 16));
        cs[0] += f0; cq[0] = fmaf(f0, f0, cq[0]);
        cs[1] += f1; cq[1] = fmaf(f1, f1, cq[1]);
        cs[2] += f2; cq[2] = fmaf(f2, f2, cq[2]);
        cs[3] += f3; cq[3] = fmaf(f3, f3, cq[3]);
        cs[4] += f4; cq[4] = fmaf(f4, f4, cq[4]);
        cs[5] += f5; cq[5] = fmaf(f5, f5, cq[5]);
        cs[6] += f6; cq[6] = fmaf(f6, f6, cq[6]);
        cs[7] += f7; cq[7] = fmaf(f7, f7, cq[7]);
    }
    // reduce over the 8 'a' groups (lanes differing in bits 3..5)
#pragma unroll
    for (int k = 0; k < 8; ++k) {
#pragma unroll
        for (int off = 8; off < 64; off <<= 1) {
            cs[k] += __shfl_xor(cs[k], off, 64);
            cq[k] += __shfl_xor(cq[k], off, 64);
        }
    }
    if (a == 0) {   // lanes 0..7 write channel block 8*e..8*e+7 directly
#pragma unroll
        for (int k = 0; k < 8; ++k) {
            part[(size_t)blk * 128 + e * 8 + k]      = cs[k];
            part[(size_t)blk * 128 + 64 + e * 8 + k] = cq[k];
        }
    }
}

// ---- per-batch GN finalize + gate MLP + fused weights (one block per b) -----
__global__ __launch_bounds__(128) void k_gateB(const float* __restrict__ part,
                                               const float* __restrict__ gn_scale,
                                               const float* __restrict__ gn_bias,
                                               const float* __restrict__ w1,
                                               const float* __restrict__ b1,
                                               const float* __restrict__ w2,
                                               const float* __restrict__ b2,
                                               const float* __restrict__ fw,
                                               float* __restrict__ sA,
                                               float* __restrict__ sB,
                                               float* __restrict__ wef) {
    const int b = blockIdx.x, t = threadIdx.x;   // t 0..127
    __shared__ float sh_s[64], sh_q[64], sh_p[64], sh_h[16];
    // coalesced reduction over 400 chunks: q = t (0..63 sum, 64..127 sumsq)
    const float* pb = part + (size_t)b * 400 * 128 + t;
    float s = 0.f;
#pragma unroll 4
    for (int k = 0; k < 400; ++k) s += pb[(size_t)k * 128];
    if (t < 64) sh_s[t] = s; else sh_q[t - 64] = s;
    __syncthreads();
    if (t < 64) {
        int c = t, g = c & ~7;
        float gs = 0.f, gq = 0.f;
#pragma unroll
        for (int i = 0; i < 8; ++i) { gs += sh_s[g + i]; gq += sh_q[g + i]; }
        const float invN = 1.0f / (8.0f * HW2D);
        float mean = gs * invN;
        float var = gq * invN - mean * mean;
        float rstd = rsqrtf(var + 1e-5f);
        float A = rstd * gn_scale[c];
        float Bv = gn_bias[c] - mean * A;
        sA[b * 64 + c] = A;
        sB[b * 64 + c] = Bv;
        sh_p[c] = fmaf(sh_s[c] * (1.0f / HW2D), A, Bv);   // post-affine ch mean
    }
    __syncthreads();
    if (t < 16) {
        float h = b1[t];
        for (int i = 0; i < 64; ++i) h = fmaf(sh_p[i], w1[t * 64 + i], h);
        sh_h[t] = fmaxf(h, 0.f);
    }
    __syncthreads();
    if (t < 64) {
        float g = b2[t];
#pragma unroll
        for (int j = 0; j < 16; ++j) g = fmaf(sh_h[j], w2[t * 16 + j], g);
        float gamma = 1.0f / (1.0f + expf(-g));
        wef[b * 64 + t] = fw[t] + gamma * fw[CR + t];
    }
}

// ---- stencil on NHWC raw y1, affine folded with exact border corrections ----
// tile 16x4 px; halo 6x18 px, all 64 ch staged once (pad 66 ushorts/px).
// Each wave computes 16 channels for all 64 px. abuf <- 1 + 0.1*sigmoid(logit)
__global__ __launch_bounds__(256) void k_sten(const unsigned short* __restrict__ y1,
                                              const float* __restrict__ sA,
                                              const float* __restrict__ sB,
                                              const float* __restrict__ wef,
                                              float* __restrict__ abuf) {
    const int tw = blockIdx.x * 16, th = blockIdx.y * 4, b = blockIdx.z;
    __shared__ unsigned short hal[108 * 66];   // 6 rows x 18 cols, px-major
    __shared__ float sh_part[4][64];
    const int t = threadIdx.x;
    const int w = __builtin_amdgcn_readfirstlane(t >> 6);
    const int lane = t & 63;
    const unsigned short* yb = y1 + (size_t)b * HW2D * 64;

#pragma unroll
    for (int it = 0; it < 4; ++it) {
        int i = t + it * 256;
        if (i < 864) {                         // 108 px * 8 chunks of 16B
            int pxi = i >> 3, c8 = (i & 7) * 8;
            int r = pxi / 18, u = pxi - r * 18;
            int gh = th + r - 1, gw = tw + u - 1;
            uint4 v; v.x = 0u; v.y = 0u; v.z = 0u; v.w = 0u;
            if ((unsigned)gh < 160u && (unsigned)gw < 160u)
                v = *(const uint4*)(yb + ((size_t)(gh * W_ + gw)) * 64 + c8);
            int d = pxi * 66 + c8;             // even -> 4B aligned
            *(unsigned*)&hal[d]     = v.x;
            *(unsigned*)&hal[d + 2] = v.y;
            *(unsigned*)&hal[d + 4] = v.z;
            *(unsigned*)&hal[d + 6] = v.w;
        }
    }
    __syncthreads();

    const int col = lane & 15, prow = lane >> 4;      // px (th+prow, tw+col)
    const int gh = th + prow, gw = tw + col;
    const int top = (gh == 0), bot = (gh == 159), lef = (gw == 0), rig = (gw == 159);
    // zero-pad-after-affine corrections (exact; all zero in interior)
    const float n9  = (float)(3 * (top + bot) + 3 * (lef + rig) -
                              (top + bot) * (lef + rig)) * (1.f / 9.f);
    const float sOx = (float)(lef - rig) * (float)(4 - top - bot) * 0.25f;
    const float sOy = (float)(top - bot) * (float)(4 - lef - rig) * 0.25f;
    const int p0 = prow * 18 + col;                   // window top-left halo px
    const int bc = b * 64;
    const int c0 = w * 16;
    float logit = 0.f;
#pragma unroll
    for (int cp = 0; cp < 8; ++cp) {
        int c = c0 + cp * 2;
        unsigned u00 = *(const unsigned*)&hal[(p0     ) * 66 + c];
        unsigned u01 = *(const unsigned*)&hal[(p0 +  1) * 66 + c];
        unsigned u02 = *(const unsigned*)&hal[(p0 +  2) * 66 + c];
        unsigned u10 = *(const unsigned*)&hal[(p0 + 18) * 66 + c];
        unsigned u11 = *(const unsigned*)&hal[(p0 + 19) * 66 + c];
        unsigned u12 = *(const unsigned*)&hal[(p0 + 20) * 66 + c];
        unsigned u20 = *(const unsigned*)&hal[(p0 + 36) * 66 + c];
        unsigned u21 = *(const unsigned*)&hal[(p0 + 37) * 66 + c];
        unsigned u22 = *(const unsigned*)&hal[(p0 + 38) * 66 + c];
        float A0 = sA[bc + c],     B0 = sB[bc + c],     wf0 = wef[bc + c];
        float A1 = sA[bc + c + 1], B1 = sB[bc + c + 1], wf1 = wef[bc + c + 1];
        {   // channel c (low halves)
            float v00 = bf2f((unsigned short)u00), v01 = bf2f((unsigned short)u01);
            float v02 = bf2f((unsigned short)u02), v10 = bf2f((unsigned short)u10);
            float v11 = bf2f((unsigned short)u11), v12 = bf2f((unsigned short)u12);
            float v20 = bf2f((unsigned short)u20), v21 = bf2f((unsigned short)u21);
            float v22 = bf2f((unsigned short)u22);
            float S = (v00 + v01 + v02) + (v10 + v11 + v12) + (v20 + v21 + v22);
            float gxr = (v00 - v02 + 2.f * (v10 - v12) + v20 - v22) * 0.25f;
            float gyr = (v00 - v20 + 2.f * (v01 - v21) + v02 - v22) * 0.25f;
            float dev = fmaf(A0, v11 - S * (1.f / 9.f), B0 * n9);
            float gx  = fmaf(A0, gxr, -B0 * sOx);
            float gy  = fmaf(A0, gyr, -B0 * sOy);
            float ratio = fminf(fabsf(dev) / (fabsf(gx) + fabsf(gy) + 1e-4f), 2.f);
            logit = fmaf(wf0, 1.f - ratio, logit);
        }
        {   // channel c+1 (high halves)
            float v00 = bf2f((unsigned short)(u00 >> 16)), v01 = bf2f((unsigned short)(u01 >> 16));
            float v02 = bf2f((unsigned short)(u02 >> 16)), v10 = bf2f((unsigned short)(u10 >> 16));
            float v11 = bf2f((unsigned short)(u11 >> 16)), v12 = bf2f((unsigned short)(u12 >> 16));
            float v20 = bf2f((unsigned short)(u20 >> 16)), v21 = bf2f((unsigned short)(u21 >> 16));
            float v22 = bf2f((unsigned short)(u22 >> 16));
            float S = (v00 + v01 + v02) + (v10 + v11 + v12) + (v20 + v21 + v22);
            float gxr = (v00 - v02 + 2.f * (v10 - v12) + v20 - v22) * 0.25f;
            float gyr = (v00 - v20 + 2.f * (v01 - v21) + v02 - v22) * 0.25f;
            float dev = fmaf(A1, v11 - S * (1.f / 9.f), B1 * n9);
            float gx  = fmaf(A1, gxr, -B1 * sOx);
            float gy  = fmaf(A1, gyr, -B1 * sOy);
            float ratio = fminf(fabsf(dev) / (fabsf(gx) + fabsf(gy) + 1e-4f), 2.f);
            logit = fmaf(wf1, 1.f - ratio, logit);
        }
    }
    sh_part[w][lane] = logit;
    __syncthreads();
    if (t < 64) {
        float l = sh_part[0][t] + sh_part[1][t] + sh_part[2][t] + sh_part[3][t];
        float av = fmaf(0.1f, 1.f / (1.f + expf(-l)), 1.f);
        abuf[(size_t)b * HW2D + (th + (t >> 4)) * W_ + tw + (t & 15)] = av;
    }
}

// ---------------- out = x * av, div-free grid mapping ------------------------
__global__ __launch_bounds__(256) void k_apply(const float* __restrict__ x,
                                               const float* __restrict__ abuf,
                                               float* __restrict__ out) {
    int px4 = blockIdx.x * 256 + threadIdx.x;   // 0..6399
    int c = blockIdx.y, b = blockIdx.z;
    size_t xi = ((size_t)(b * NC + c)) * (HW2D / 4) + px4;
    float4 xv = ((const float4*)x)[xi];
    float4 av = ((const float4*)abuf)[b * (HW2D / 4) + px4];
    float4 ov;
    ov.x = xv.x * av.x;
    ov.y = xv.y * av.y;
    ov.z = xv.z * av.z;
    ov.w = xv.w * av.w;
    ((float4*)out)[xi] = ov;
}

extern "C" void kernel_launch(void* const* d_in, const int* in_sizes, int n_in,
                              void* d_out, int out_size, void* d_ws, size_t ws_size,
                              hipStream_t stream) {
    const float* x   = (const float*)d_in[0];
    const float* rw  = (const float*)d_in[1];
    const float* gns = (const float*)d_in[2];
    const float* gnb = (const float*)d_in[3];
    const float* w1  = (const float*)d_in[4];
    const float* b1  = (const float*)d_in[5];
    const float* w2  = (const float*)d_in[6];
    const float* b2  = (const float*)d_in[7];
    const float* fw  = (const float*)d_in[8];
    float* out = (float*)d_out;

    float* ws    = (float*)d_ws;
    float* sA    = ws;                               // 512
    float* sB    = sA + 512;
    float* wef   = sB + 512;
    float* part  = wef + 512;                        // 3200*128 = 409600
    float* abuf  = part + 409600;                    // 204800
    short* aPack = (short*)(abuf + 204800);          // 16384 shorts (32 KB)
    unsigned short* y1 = (unsigned short*)(aPack + 16384);  // 13,107,200 ushorts NHWC

    hipLaunchKernelGGL(k_pack,  dim3(8),           dim3(256), 0, stream, rw, aPack);
    hipLaunchKernelGGL(k_rmfma, dim3(3200),        dim3(64),  0, stream, x, aPack, y1, part);
    hipLaunchKernelGGL(k_gateB, dim3(8),           dim3(128), 0, stream,
                       part, gns, gnb, w1, b1, w2, b2, fw, sA, sB, wef);
    hipLaunchKernelGGL(k_sten,  dim3(10, 40, 8),   dim3(256), 0, stream, y1, sA, sB, wef, abuf);
    hipLaunchKernelGGL(k_apply, dim3(25, 256, 8),  dim3(256), 0, stream, x, abuf, out);
}

// Round 16
// 151.374 us; speedup vs baseline: 1.1665x; 1.1665x over previous
//
#include <hip/hip_runtime.h>
#include <hip/hip_bf16.h>
#include <math.h>

#define HW2D 25600      // 160*160
#define NB 8
#define NC 256
#define CR 64
#define H_ 160
#define W_ 160

typedef short bf16x8 __attribute__((ext_vector_type(8)));
typedef float f32x4 __attribute__((ext_vector_type(4)));

__device__ __forceinline__ short f2bf(float f) {
    __hip_bfloat16 h = __float2bfloat16(f);   // v_cvt_pk_bf16_f32 pairs
    return *reinterpret_cast<short*>(&h);
}
__device__ __forceinline__ float bf2f(unsigned short b) {
    union { unsigned u; float f; } v; v.u = ((unsigned)b) << 16;
    return v.f;
}

// ---- pack reduce_w into MFMA A-fragment order: aPack[(s*4+m)*64+lane][8] ----
__global__ __launch_bounds__(256) void k_pack(const float* __restrict__ rw,
                                              short* __restrict__ aPack) {
    int t = blockIdx.x * 256 + threadIdx.x;   // 0..2047
    if (t >= 2048) return;
    int s = t >> 8, m = (t >> 6) & 3, lane = t & 63;
    int row = m * 16 + (lane & 15);           // output o within [0,64)
    int k0 = s * 32 + (lane >> 4) * 8;        // channel c
    short* dst = aPack + ((size_t)((s * 4 + m) * 64 + lane)) * 8;
#pragma unroll
    for (int j = 0; j < 8; ++j)
        dst[j] = f2bf(rw[row * NC + k0 + j]);
}

// ---- y1[b,px,o] (NHWC bf16) = sum_c W[o,c]*x[b,c,px] via MFMA --------------
// dwordx4 x-loads: B-column c of n-tile n <-> px = pxb + 4c + n (free remap),
// so each lane loads ONE float4 per channel feeding all 4 n-tiles.
// 64 px per wave, 256 px per block, grid 800. Emits per-block GN partials
// part[blk*128 + {0..63 sum, 64..127 sumsq}] from the SAME bf16-rounded values.
__global__ __launch_bounds__(256) void k_rmfma(const float* __restrict__ x,
                                               const short* __restrict__ aPack,
                                               unsigned short* __restrict__ y1,
                                               float* __restrict__ part) {
    int wave = __builtin_amdgcn_readfirstlane(threadIdx.x >> 6);  // SGPR wave id
    int lane = threadIdx.x & 63;
    int blk = blockIdx.x;                          // 0..799
    int b = blk / 100;
    int pxb = (blk - b * 100) * 256 + wave * 64;   // wave-uniform (SGPR)
    int l15 = lane & 15, kg = lane >> 4;
    int laneoff = kg * 8 * HW2D + 4 * l15;         // per-lane 32-bit offset
    const float* xw = x + (size_t)b * NC * HW2D + pxb;   // SGPR base
    f32x4 acc[4][4];
    f32x4 zz = {0.f, 0.f, 0.f, 0.f};
#pragma unroll
    for (int m = 0; m < 4; ++m)
#pragma unroll
        for (int n = 0; n < 4; ++n) acc[m][n] = zz;
    const bf16x8* ap = (const bf16x8*)aPack + lane;
#pragma unroll
    for (int s = 0; s < 8; ++s) {
        bf16x8 a0 = ap[(s * 4 + 0) * 64];
        bf16x8 a1 = ap[(s * 4 + 1) * 64];
        bf16x8 a2 = ap[(s * 4 + 2) * 64];
        bf16x8 a3 = ap[(s * 4 + 3) * 64];
        const float* xs = xw + s * 32 * HW2D + laneoff;
        bf16x8 b0, b1, b2, b3;
#pragma unroll
        for (int j = 0; j < 8; ++j) {
            float4 v = *(const float4*)(xs + (size_t)j * HW2D);
            b0[j] = f2bf(v.x);                 // px = pxb + 4*l15 + 0
            b1[j] = f2bf(v.y);                 // px = pxb + 4*l15 + 1
            b2[j] = f2bf(v.z);                 // px = pxb + 4*l15 + 2
            b3[j] = f2bf(v.w);                 // px = pxb + 4*l15 + 3
        }
        acc[0][0] = __builtin_amdgcn_mfma_f32_16x16x32_bf16(a0, b0, acc[0][0], 0, 0, 0);
        acc[0][1] = __builtin_amdgcn_mfma_f32_16x16x32_bf16(a0, b1, acc[0][1], 0, 0, 0);
        acc[0][2] = __builtin_amdgcn_mfma_f32_16x16x32_bf16(a0, b2, acc[0][2], 0, 0, 0);
        acc[0][3] = __builtin_amdgcn_mfma_f32_16x16x32_bf16(a0, b3, acc[0][3], 0, 0, 0);
        acc[1][0] = __builtin_amdgcn_mfma_f32_16x16x32_bf16(a1, b0, acc[1][0], 0, 0, 0);
        acc[1][1] = __builtin_amdgcn_mfma_f32_16x16x32_bf16(a1, b1, acc[1][1], 0, 0, 0);
        acc[1][2] = __builtin_amdgcn_mfma_f32_16x16x32_bf16(a1, b2, acc[1][2], 0, 0, 0);
        acc[1][3] = __builtin_amdgcn_mfma_f32_16x16x32_bf16(a1, b3, acc[1][3], 0, 0, 0);
        acc[2][0] = __builtin_amdgcn_mfma_f32_16x16x32_bf16(a2, b0, acc[2][0], 0, 0, 0);
        acc[2][1] = __builtin_amdgcn_mfma_f32_16x16x32_bf16(a2, b1, acc[2][1], 0, 0, 0);
        acc[2][2] = __builtin_amdgcn_mfma_f32_16x16x32_bf16(a2, b2, acc[2][2], 0, 0, 0);
        acc[2][3] = __builtin_amdgcn_mfma_f32_16x16x32_bf16(a2, b3, acc[2][3], 0, 0, 0);
        acc[3][0] = __builtin_amdgcn_mfma_f32_16x16x32_bf16(a3, b0, acc[3][0], 0, 0, 0);
        acc[3][1] = __builtin_amdgcn_mfma_f32_16x16x32_bf16(a3, b1, acc[3][1], 0, 0, 0);
        acc[3][2] = __builtin_amdgcn_mfma_f32_16x16x32_bf16(a3, b2, acc[3][2], 0, 0, 0);
        acc[3][3] = __builtin_amdgcn_mfma_f32_16x16x32_bf16(a3, b3, acc[3][3], 0, 0, 0);
    }
    // --- transpose 64px x 64ch to NHWC via wave-private LDS (pad 66) ---------
    // C/D: out-ch o = m*16 + kg*4 + i; px slot = 4*l15 + n (column remap)
    __shared__ unsigned short tr[4][64 * 66];
    __shared__ float st_s[4][64], st_q[4][64];
    unsigned short* trw = tr[wave];
#pragma unroll
    for (int m = 0; m < 4; ++m)
#pragma unroll
        for (int n = 0; n < 4; ++n)
#pragma unroll
            for (int i = 0; i < 4; i += 2) {
                unsigned short r0 = (unsigned short)f2bf(acc[m][n][i]);
                unsigned short r1 = (unsigned short)f2bf(acc[m][n][i + 1]);
                unsigned v = (unsigned)r0 | ((unsigned)r1 << 16);
                int o = m * 16 + kg * 4 + i;              // even
                *(unsigned*)&trw[(4 * l15 + n) * 66 + o] = v;
            }
    // readback px-slot-major + coalesced NHWC stores + stats accumulation
    float cs[8], cq[8];
#pragma unroll
    for (int k = 0; k < 8; ++k) { cs[k] = 0.f; cq[k] = 0.f; }
    unsigned short* yg = y1 + ((size_t)b * HW2D + pxb) * 64;
    const int e = lane & 7, a = lane >> 3;
#pragma unroll
    for (int j = 0; j < 8; ++j) {
        int p = j * 8 + a;                                // px slot 0..63
        int dbase = p * 66 + e * 8;                       // even ushort idx
        unsigned q0 = *(const unsigned*)&trw[dbase];
        unsigned q1 = *(const unsigned*)&trw[dbase + 2];
        unsigned q2 = *(const unsigned*)&trw[dbase + 4];
        unsigned q3 = *(const unsigned*)&trw[dbase + 6];
        uint4 vv; vv.x = q0; vv.y = q1; vv.z = q2; vv.w = q3;
        *(uint4*)(yg + (size_t)p * 64 + e * 8) = vv;
        float f0 = bf2f((unsigned short)(q0 & 0xffff)), f1 = bf2f((unsigned short)(q0 >> 16));
        float f2 = bf2f((unsigned short)(q1 & 0xffff)), f3 = bf2f((unsigned short)(q1 >> 16));
        float f4 = bf2f((unsigned short)(q2 & 0xffff)), f5 = bf2f((unsigned short)(q2 >> 16));
        float f6 = bf2f((unsigned short)(q3 & 0xffff)), f7 = bf2f((unsigned short)(q3 >> 16));
        cs[0] += f0; cq[0] = fmaf(f0, f0, cq[0]);
        cs[1] += f1; cq[1] = fmaf(f1, f1, cq[1]);
        cs[2] += f2; cq[2] = fmaf(f2, f2, cq[2]);
        cs[3] += f3; cq[3] = fmaf(f3, f3, cq[3]);
        cs[4] += f4; cq[4] = fmaf(f4, f4, cq[4]);
        cs[5] += f5; cq[5] = fmaf(f5, f5, cq[5]);
        cs[6] += f6; cq[6] = fmaf(f6, f6, cq[6]);
        cs[7] += f7; cq[7] = fmaf(f7, f7, cq[7]);
    }
    // reduce over the 8 'a' groups (lanes differing in bits 3..5)
#pragma unroll
    for (int k = 0; k < 8; ++k) {
#pragma unroll
        for (int off = 8; off < 64; off <<= 1) {
            cs[k] += __shfl_xor(cs[k], off, 64);
            cq[k] += __shfl_xor(cq[k], off, 64);
        }
    }
    if (a == 0) {   // lanes 0..7: channel block 8*e..8*e+7
#pragma unroll
        for (int k = 0; k < 8; ++k) {
            st_s[wave][e * 8 + k] = cs[k];
            st_q[wave][e * 8 + k] = cq[k];
        }
    }
    __syncthreads();
    int tt = threadIdx.x;
    if (tt < 64)
        part[(size_t)blk * 128 + tt] = st_s[0][tt] + st_s[1][tt] + st_s[2][tt] + st_s[3][tt];
    else if (tt < 128)
        part[(size_t)blk * 128 + tt] =
            st_q[0][tt - 64] + st_q[1][tt - 64] + st_q[2][tt - 64] + st_q[3][tt - 64];
}

// ---- per-batch GN finalize + gate MLP + fused weights (one block per b) -----
__global__ __launch_bounds__(128) void k_gateB(const float* __restrict__ part,
                                               const float* __restrict__ gn_scale,
                                               const float* __restrict__ gn_bias,
                                               const float* __restrict__ w1,
                                               const float* __restrict__ b1,
                                               const float* __restrict__ w2,
                                               const float* __restrict__ b2,
                                               const float* __restrict__ fw,
                                               float* __restrict__ sA,
                                               float* __restrict__ sB,
                                               float* __restrict__ wef) {
    const int b = blockIdx.x, t = threadIdx.x;   // t 0..127
    __shared__ float sh_s[64], sh_q[64], sh_p[64], sh_h[16];
    // coalesced reduction over 100 chunks: q = t (0..63 sum, 64..127 sumsq)
    const float* pb = part + (size_t)b * 100 * 128 + t;
    float s = 0.f;
#pragma unroll 4
    for (int k = 0; k < 100; ++k) s += pb[(size_t)k * 128];
    if (t < 64) sh_s[t] = s; else sh_q[t - 64] = s;
    __syncthreads();
    if (t < 64) {
        int c = t, g = c & ~7;
        float gs = 0.f, gq = 0.f;
#pragma unroll
        for (int i = 0; i < 8; ++i) { gs += sh_s[g + i]; gq += sh_q[g + i]; }
        const float invN = 1.0f / (8.0f * HW2D);
        float mean = gs * invN;
        float var = gq * invN - mean * mean;
        float rstd = rsqrtf(var + 1e-5f);
        float A = rstd * gn_scale[c];
        float Bv = gn_bias[c] - mean * A;
        sA[b * 64 + c] = A;
        sB[b * 64 + c] = Bv;
        sh_p[c] = fmaf(sh_s[c] * (1.0f / HW2D), A, Bv);   // post-affine ch mean
    }
    __syncthreads();
    if (t < 16) {
        float h = b1[t];
        for (int i = 0; i < 64; ++i) h = fmaf(sh_p[i], w1[t * 64 + i], h);
        sh_h[t] = fmaxf(h, 0.f);
    }
    __syncthreads();
    if (t < 64) {
        float g = b2[t];
#pragma unroll
        for (int j = 0; j < 16; ++j) g = fmaf(sh_h[j], w2[t * 16 + j], g);
        float gamma = 1.0f / (1.0f + expf(-g));
        wef[b * 64 + t] = fw[t] + gamma * fw[CR + t];
    }
}

// ---- stencil on NHWC raw y1, affine folded with exact border corrections ----
// tile 16x4 px; halo 6x18 px, all 64 ch staged once (pad 66 ushorts/px).
// Each wave computes 16 channels for all 64 px. abuf <- 1 + 0.1*sigmoid(logit)
__global__ __launch_bounds__(256) void k_sten(const unsigned short* __restrict__ y1,
                                              const float* __restrict__ sA,
                                              const float* __restrict__ sB,
                                              const float* __restrict__ wef,
                                              float* __restrict__ abuf) {
    const int tw = blockIdx.x * 16, th = blockIdx.y * 4, b = blockIdx.z;
    __shared__ unsigned short hal[108 * 66];   // 6 rows x 18 cols, px-major
    __shared__ float sh_part[4][64];
    const int t = threadIdx.x;
    const int w = __builtin_amdgcn_readfirstlane(t >> 6);
    const int lane = t & 63;
    const unsigned short* yb = y1 + (size_t)b * HW2D * 64;

#pragma unroll
    for (int it = 0; it < 4; ++it) {
        int i = t + it * 256;
        if (i < 864) {                         // 108 px * 8 chunks of 16B
            int pxi = i >> 3, c8 = (i & 7) * 8;
            int r = pxi / 18, u = pxi - r * 18;
            int gh = th + r - 1, gw = tw + u - 1;
            uint4 v; v.x = 0u; v.y = 0u; v.z = 0u; v.w = 0u;
            if ((unsigned)gh < 160u && (unsigned)gw < 160u)
                v = *(const uint4*)(yb + ((size_t)(gh * W_ + gw)) * 64 + c8);
            int d = pxi * 66 + c8;             // even -> 4B aligned
            *(unsigned*)&hal[d]     = v.x;
            *(unsigned*)&hal[d + 2] = v.y;
            *(unsigned*)&hal[d + 4] = v.z;
            *(unsigned*)&hal[d + 6] = v.w;
        }
    }
    __syncthreads();

    const int col = lane & 15, prow = lane >> 4;      // px (th+prow, tw+col)
    const int gh = th + prow, gw = tw + col;
    const int top = (gh == 0), bot = (gh == 159), lef = (gw == 0), rig = (gw == 159);
    // zero-pad-after-affine corrections (exact; all zero in interior)
    const float n9  = (float)(3 * (top + bot) + 3 * (lef + rig) -
                              (top + bot) * (lef + rig)) * (1.f / 9.f);
    const float sOx = (float)(lef - rig) * (float)(4 - top - bot) * 0.25f;
    const float sOy = (float)(top - bot) * (float)(4 - lef - rig) * 0.25f;
    const int p0 = prow * 18 + col;                   // window top-left halo px
    const int bc = b * 64;
    const int c0 = w * 16;
    float logit = 0.f;
#pragma unroll
    for (int cp = 0; cp < 8; ++cp) {
        int c = c0 + cp * 2;
        unsigned u00 = *(const unsigned*)&hal[(p0     ) * 66 + c];
        unsigned u01 = *(const unsigned*)&hal[(p0 +  1) * 66 + c];
        unsigned u02 = *(const unsigned*)&hal[(p0 +  2) * 66 + c];
        unsigned u10 = *(const unsigned*)&hal[(p0 + 18) * 66 + c];
        unsigned u11 = *(const unsigned*)&hal[(p0 + 19) * 66 + c];
        unsigned u12 = *(const unsigned*)&hal[(p0 + 20) * 66 + c];
        unsigned u20 = *(const unsigned*)&hal[(p0 + 36) * 66 + c];
        unsigned u21 = *(const unsigned*)&hal[(p0 + 37) * 66 + c];
        unsigned u22 = *(const unsigned*)&hal[(p0 + 38) * 66 + c];
        float A0 = sA[bc + c],     B0 = sB[bc + c],     wf0 = wef[bc + c];
        float A1 = sA[bc + c + 1], B1 = sB[bc + c + 1], wf1 = wef[bc + c + 1];
        {   // channel c (low halves)
            float v00 = bf2f((unsigned short)u00), v01 = bf2f((unsigned short)u01);
            float v02 = bf2f((unsigned short)u02), v10 = bf2f((unsigned short)u10);
            float v11 = bf2f((unsigned short)u11), v12 = bf2f((unsigned short)u12);
            float v20 = bf2f((unsigned short)u20), v21 = bf2f((unsigned short)u21);
            float v22 = bf2f((unsigned short)u22);
            float S = (v00 + v01 + v02) + (v10 + v11 + v12) + (v20 + v21 + v22);
            float gxr = (v00 - v02 + 2.f * (v10 - v12) + v20 - v22) * 0.25f;
            float gyr = (v00 - v20 + 2.f * (v01 - v21) + v02 - v22) * 0.25f;
            float dev = fmaf(A0, v11 - S * (1.f / 9.f), B0 * n9);
            float gx  = fmaf(A0, gxr, -B0 * sOx);
            float gy  = fmaf(A0, gyr, -B0 * sOy);
            float ratio = fminf(fabsf(dev) / (fabsf(gx) + fabsf(gy) + 1e-4f), 2.f);
            logit = fmaf(wf0, 1.f - ratio, logit);
        }
        {   // channel c+1 (high halves)
            float v00 = bf2f((unsigned short)(u00 >> 16)), v01 = bf2f((unsigned short)(u01 >> 16));
            float v02 = bf2f((unsigned short)(u02 >> 16)), v10 = bf2f((unsigned short)(u10 >> 16));
            float v11 = bf2f((unsigned short)(u11 >> 16)), v12 = bf2f((unsigned short)(u12 >> 16));
            float v20 = bf2f((unsigned short)(u20 >> 16)), v21 = bf2f((unsigned short)(u21 >> 16));
            float v22 = bf2f((unsigned short)(u22 >> 16));
            float S = (v00 + v01 + v02) + (v10 + v11 + v12) + (v20 + v21 + v22);
            float gxr = (v00 - v02 + 2.f * (v10 - v12) + v20 - v22) * 0.25f;
            float gyr = (v00 - v20 + 2.f * (v01 - v21) + v02 - v22) * 0.25f;
            float dev = fmaf(A1, v11 - S * (1.f / 9.f), B1 * n9);
            float gx  = fmaf(A1, gxr, -B1 * sOx);
            float gy  = fmaf(A1, gyr, -B1 * sOy);
            float ratio = fminf(fabsf(dev) / (fabsf(gx) + fabsf(gy) + 1e-4f), 2.f);
            logit = fmaf(wf1, 1.f - ratio, logit);
        }
    }
    sh_part[w][lane] = logit;
    __syncthreads();
    if (t < 64) {
        float l = sh_part[0][t] + sh_part[1][t] + sh_part[2][t] + sh_part[3][t];
        float av = fmaf(0.1f, 1.f / (1.f + expf(-l)), 1.f);
        abuf[(size_t)b * HW2D + (th + (t >> 4)) * W_ + tw + (t & 15)] = av;
    }
}

// ---------------- out = x * av, div-free grid mapping ------------------------
__global__ __launch_bounds__(256) void k_apply(const float* __restrict__ x,
                                               const float* __restrict__ abuf,
                                               float* __restrict__ out) {
    int px4 = blockIdx.x * 256 + threadIdx.x;   // 0..6399
    int c = blockIdx.y, b = blockIdx.z;
    size_t xi = ((size_t)(b * NC + c)) * (HW2D / 4) + px4;
    float4 xv = ((const float4*)x)[xi];
    float4 av = ((const float4*)abuf)[b * (HW2D / 4) + px4];
    float4 ov;
    ov.x = xv.x * av.x;
    ov.y = xv.y * av.y;
    ov.z = xv.z * av.z;
    ov.w = xv.w * av.w;
    ((float4*)out)[xi] = ov;
}

extern "C" void kernel_launch(void* const* d_in, const int* in_sizes, int n_in,
                              void* d_out, int out_size, void* d_ws, size_t ws_size,
                              hipStream_t stream) {
    const float* x   = (const float*)d_in[0];
    const float* rw  = (const float*)d_in[1];
    const float* gns = (const float*)d_in[2];
    const float* gnb = (const float*)d_in[3];
    const float* w1  = (const float*)d_in[4];
    const float* b1  = (const float*)d_in[5];
    const float* w2  = (const float*)d_in[6];
    const float* b2  = (const float*)d_in[7];
    const float* fw  = (const float*)d_in[8];
    float* out = (float*)d_out;

    float* ws    = (float*)d_ws;
    float* sA    = ws;                               // 512
    float* sB    = sA + 512;
    float* wef   = sB + 512;
    float* part  = wef + 512;                        // 800*128 = 102400
    float* abuf  = part + 102400;                    // 204800
    short* aPack = (short*)(abuf + 204800);          // 16384 shorts (32 KB)
    unsigned short* y1 = (unsigned short*)(aPack + 16384);  // 13,107,200 ushorts NHWC

    hipLaunchKernelGGL(k_pack,  dim3(8),           dim3(256), 0, stream, rw, aPack);
    hipLaunchKernelGGL(k_rmfma, dim3(800),         dim3(256), 0, stream, x, aPack, y1, part);
    hipLaunchKernelGGL(k_gateB, dim3(8),           dim3(128), 0, stream,
                       part, gns, gnb, w1, b1, w2, b2, fw, sA, sB, wef);
    hipLaunchKernelGGL(k_sten,  dim3(10, 40, 8),   dim3(256), 0, stream, y1, sA, sB, wef, abuf);
    hipLaunchKernelGGL(k_apply, dim3(25, 256, 8),  dim3(256), 0, stream, x, abuf, out);
}